// Round 8
// baseline (109826.538 us; speedup 1.0000x reference)
//
#include <hip/hip_runtime.h>
#include <cstdint>
#include <cstddef>

#define BDIM 512
#define NWG  192

constexpr int B_ = 64, S_ = 1024, I_ = 128, H_ = 512, O_ = 128;
constexpr size_t HB = (size_t)H_ * B_;   // 32768 floats per slab [k][b]

// ---- workspace (floats): y1/y2 rings, rh/z slabs, barrier, XN ring, XT ----
constexpr size_t Y1_OFF  = 0;                 // 2 slots
constexpr size_t Y2_OFF  = Y1_OFF + 2 * HB;   // 2 slots
constexpr size_t RH0_OFF = Y2_OFF + 2 * HB;
constexpr size_t RH1_OFF = RH0_OFF + HB;
constexpr size_t Z0_OFF  = RH1_OFF + HB;
constexpr size_t Z1_OFF  = Z0_OFF + HB;
constexpr size_t BAR_OFF = Z1_OFF + HB;       // 2 halves x 17 lines x 64 uints
constexpr size_t BAR_WORDS = 34 * 64;
constexpr size_t XN_OFF  = BAR_OFF + BAR_WORDS;   // precomputed L0 x-proj: 2 slots x 1536x64
constexpr size_t XN_SLOT = (size_t)1536 * 64;
constexpr size_t XT_OFF  = XN_OFF + 2 * XN_SLOT;  // [t][i][b] transposed input
constexpr size_t XT_FLOATS = (size_t)S_ * I_ * B_;
constexpr size_t WS_NEED_XT_BYTES = (XT_OFF + XT_FLOATS) * 4;

// ---------------- LLC (agent-scope, L2-bypassing) access helpers ----------------
__device__ __forceinline__ float4 llc_load4(const float* p) {
  const unsigned long long* q = (const unsigned long long*)p;
  unsigned long long lo = __hip_atomic_load(q,     __ATOMIC_RELAXED, __HIP_MEMORY_SCOPE_AGENT);
  unsigned long long hi = __hip_atomic_load(q + 1, __ATOMIC_RELAXED, __HIP_MEMORY_SCOPE_AGENT);
  union { unsigned long long u[2]; float4 v; } c;
  c.u[0] = lo; c.u[1] = hi;
  return c.v;
}
__device__ __forceinline__ void llc_store4(float* p, float4 v) {
  union { float4 v; unsigned long long u[2]; } c; c.v = v;
  __hip_atomic_store((unsigned long long*)p,     c.u[0], __ATOMIC_RELAXED, __HIP_MEMORY_SCOPE_AGENT);
  __hip_atomic_store((unsigned long long*)p + 1, c.u[1], __ATOMIC_RELAXED, __HIP_MEMORY_SCOPE_AGENT);
}
__device__ __forceinline__ void llc_storef(float* p, float x) {
  union { float f; unsigned int u; } c; c.f = x;
  __hip_atomic_store((unsigned int*)p, c.u, __ATOMIC_RELAXED, __HIP_MEMORY_SCOPE_AGENT);
}

// ---------------- init: seed y1[-1]/y2[-1] at slot 1, zero barrier ----------------
__global__ void k_init(const float* __restrict__ hidden, float* __restrict__ ws) {
  int idx = blockIdx.x * 256 + threadIdx.x;           // 2*HB + BAR_WORDS items
  if (idx < (int)(2 * HB)) {
    int l = idx >> 15, r = idx & 32767;
    int k = r >> 6, b = r & 63;
    ws[(l ? Y2_OFF : Y1_OFF) + HB + r] = hidden[b * 1024 + l * 512 + k];
  } else if (idx < (int)(2 * HB + BAR_WORDS)) {
    ((unsigned int*)(ws + BAR_OFF))[idx - 2 * HB] = 0u;
  }
}

// ---------------- input transpose: XT[t][i][b] = input[b][t][i] ----------------
__global__ void k_transpose_x(const float* __restrict__ in, float* __restrict__ Xt) {
  const size_t NQ = (size_t)B_ * S_ * I_ / 4;
  for (size_t q = (size_t)blockIdx.x * blockDim.x + threadIdx.x; q < NQ;
       q += (size_t)gridDim.x * blockDim.x) {
    int i4 = (int)(q & 31);
    int t  = (int)((q >> 5) & 1023);
    int b  = (int)(q >> 15);
    float4 v = *(const float4*)(in + ((size_t)b * 1024 + t) * 128 + i4 * 4);
    float* dst = Xt + (size_t)t * 8192 + (size_t)(i4 * 4) * 64 + b;
    dst[0] = v.x; dst[64] = v.y; dst[128] = v.z; dst[192] = v.w;
  }
}

// ---------------- XN[0] pre-pass: xz0/xr0/xg0 for t=0 ----------------
// col space: [0,512) xz0, [512,1024) xr0, [1024,1536) xg0
__global__ void k_xn0(const float* __restrict__ xin, const float* __restrict__ Wzx0,
                      const float* __restrict__ Wrx0, const float* __restrict__ Wgx0,
                      float* __restrict__ ws, int use_xt) {
  int c = blockIdx.x;          // 0..1535
  int b = threadIdx.x;         // 0..63
  const float* W = (c < 512) ? Wzx0 : (c < 1024 ? Wrx0 : Wgx0);
  int lc = c & 511;
  float s = 0.f;
  if (use_xt) {
    const float* X0 = ws + XT_OFF;      // XT[0][i][b]
    for (int k = 0; k < 128; ++k) s += W[k * 512 + lc] * X0[k * 64 + b];
  } else {
    for (int k = 0; k < 128; ++k) s += W[k * 512 + lc] * xin[(size_t)b * 131072 + k];
  }
  llc_storef(ws + XN_OFF + (size_t)c * 64 + b, s);   // slot 0
}

// ---------------- fma helpers ----------------
__device__ __forceinline__ void fmas(float4& a, float s, const float4 h) {
  a.x = fmaf(s, h.x, a.x); a.y = fmaf(s, h.y, a.y);
  a.z = fmaf(s, h.z, a.z); a.w = fmaf(s, h.w, a.w);
}
// C=32 vs LDS [c4(8)][k(512)]
__device__ __forceinline__ void fma32L(float4* acc, const float4* w, int k, float4 h) {
  #pragma unroll
  for (int g = 0; g < 8; ++g) {
    float4 W = w[g * 512 + k];
    fmas(acc[g*4+0], W.x, h); fmas(acc[g*4+1], W.y, h);
    fmas(acc[g*4+2], W.z, h); fmas(acc[g*4+3], W.w, h);
  }
}
// C=16 vs LDS [c4(4)][k(1024)]
__device__ __forceinline__ void fma16La(float4* acc, const float4* w, int k, float4 h) {
  #pragma unroll
  for (int g = 0; g < 4; ++g) {
    float4 W = w[g * 1024 + k];
    fmas(acc[g*4+0], W.x, h); fmas(acc[g*4+1], W.y, h);
    fmas(acc[g*4+2], W.z, h); fmas(acc[g*4+3], W.w, h);
  }
}
// C=16 vs LDS [c4(4)][k(512)]
__device__ __forceinline__ void fma16Lb(float4* acc, const float4* w, int k, float4 h) {
  #pragma unroll
  for (int g = 0; g < 4; ++g) {
    float4 W = w[g * 512 + k];
    fmas(acc[g*4+0], W.x, h); fmas(acc[g*4+1], W.y, h);
    fmas(acc[g*4+2], W.z, h); fmas(acc[g*4+3], W.w, h);
  }
}
// C=8 vs LDS [c4(2)][k(1024)]
__device__ __forceinline__ void fma8La(float4* acc, const float4* w, int k, float4 h) {
  #pragma unroll
  for (int g = 0; g < 2; ++g) {
    float4 W = w[g * 1024 + k];
    fmas(acc[g*4+0], W.x, h); fmas(acc[g*4+1], W.y, h);
    fmas(acc[g*4+2], W.z, h); fmas(acc[g*4+3], W.w, h);
  }
}
// C=16 vs LDS [c4(4)][k(128)]  (x-slice)
__device__ __forceinline__ void fma16X(float4* acc, const float4* w, int k, float4 h) {
  #pragma unroll
  for (int g = 0; g < 4; ++g) {
    float4 W = w[g * 128 + k];
    fmas(acc[g*4+0], W.x, h); fmas(acc[g*4+1], W.y, h);
    fmas(acc[g*4+2], W.z, h); fmas(acc[g*4+3], W.w, h);
  }
}
// fold lane bits 3,4,5: 3 butterfly rounds; survivors (lane&56)==0, slot=wv
__device__ __forceinline__ void red3(float4& v) {
  v.x += __shfl_xor(v.x, 8);  v.y += __shfl_xor(v.y, 8);
  v.z += __shfl_xor(v.z, 8);  v.w += __shfl_xor(v.w, 8);
  v.x += __shfl_xor(v.x, 16); v.y += __shfl_xor(v.y, 16);
  v.z += __shfl_xor(v.z, 16); v.w += __shfl_xor(v.w, 16);
  v.x += __shfl_xor(v.x, 32); v.y += __shfl_xor(v.y, 32);
  v.z += __shfl_xor(v.z, 32); v.w += __shfl_xor(v.w, 32);
}

// ---- per-HALF barrier: 96 WGs = 6 groups x 16; root fans out to 6 gen lines ----
// Two batch halves are fully independent (disjoint b-ranges of every slab, disjoint
// LLC lines) -> each half syncs only its own 96 WGs; halves may drift freely.
__device__ __forceinline__ void grid_barrier(unsigned int* bh, int grp, unsigned int ph) {
  __syncthreads();
  asm volatile("" ::: "memory");
  if (threadIdx.x == 0) {
    unsigned int r = __hip_atomic_fetch_add(bh + (size_t)grp * 64, 1u,
                                            __ATOMIC_RELAXED, __HIP_MEMORY_SCOPE_AGENT);
    if (r == 16u * ph - 1u) {
      unsigned int rr = __hip_atomic_fetch_add(bh + 8 * 64, 1u,
                                               __ATOMIC_RELAXED, __HIP_MEMORY_SCOPE_AGENT);
      if (rr == 6u * ph - 1u) {
        #pragma unroll
        for (int g = 0; g < 6; ++g)
          __hip_atomic_store(bh + (size_t)(9 + g) * 64, ph,
                             __ATOMIC_RELAXED, __HIP_MEMORY_SCOPE_AGENT);
      }
    }
    while (__hip_atomic_load(bh + (size_t)(9 + grp) * 64,
                             __ATOMIC_RELAXED, __HIP_MEMORY_SCOPE_AGENT) < ph)
      __builtin_amdgcn_s_sleep(1);
  }
  asm volatile("" ::: "memory");
  __syncthreads();
}

// ---------------- persistent scan ----------------
struct ScanArgs {
  float* ws;
  const float* xin;
  float* out;
  const float *Wzx0, *Wzh0, *bz0, *Wrx0, *Wrh0, *br0, *Wgx0, *Wgh0, *bg0;
  const float *Wzx1, *Wzh1, *bz1, *Wrx1, *Wrh1, *br1, *Wgx1, *Wgh1, *bg1;
  const float *Wout, *bout;
  int use_xt;
};

// 192 WGs x 512 thr. bg=wg&1 selects batch half (b0=bg*32); hwg=wg>>1 in [0,96):
//   A: hwg<16 L0z(C=32,K=512) | <32 L0r(C=32) | <64 L1z(C=16,K=1024) | <96 L1r(C=16)
//      all roles = 16384 col*K (BALANCED). outproj fused on L1 WGs (C=2, free).
//      L0's x-part comes from the XN slab (precomputed one step ahead).
//   B: hwg<32 g0(C=16,K=512) | else g1(C=8,K=1024) -> both 8192. x-slice: every WG
//      computes 16 cols of XN[t+1] (C=16,K=128) from XT (immutable).
__launch_bounds__(BDIM, 1)
__global__ void k_scan(ScanArgs a) {
  float* ws = a.ws;
  const int tid  = threadIdx.x;
  const int wg   = blockIdx.x;
  const int lane = tid & 63;
  const int wv   = tid >> 6;                 // 0..7
  const int kt   = (wv << 3) | (lane >> 3);  // 0..63
  const int bq   = lane & 7;
  const int b4   = bq << 2;

  const int  bg   = wg & 1;
  const int  hwg  = wg >> 1;                 // 0..95
  const int  b0   = bg * 32;
  const bool isL1A = (hwg >= 32);
  const int  gA   = isL1A ? (hwg >= 64) : (hwg >= 16);    // 0 z, 1 r
  const int  CA   = isL1A ? 16 : 32;
  const int  jA0  = isL1A ? ((hwg - 32 - (gA ? 32 : 0)) * 16)
                          : ((hwg - (gA ? 16 : 0)) * 32);
  const int  jO   = isL1A ? ((hwg - 32) * 2) : 0;
  const bool isG0 = (hwg < 32);
  const int  CB   = isG0 ? 16 : 8;
  const int  jB0  = isG0 ? (hwg * 16) : ((hwg - 32) * 8);
  const int  jX0  = hwg * 16;                // x-slice cols [jX0, jX0+16)
  const int  grp  = hwg >> 4;                // 0..5
  unsigned int* bhalf = (unsigned int*)(ws + BAR_OFF) + (size_t)bg * (17 * 64);

  __shared__ float4 wA4[4096];    // 64KB  A weights
  __shared__ float4 wB4[2048];    // 32KB  B weights
  __shared__ float4 xw4[512];     // 8KB   x-slice weights [c4(4)][k(128)]
  __shared__ float2 wO2[512];     // 4KB   outproj col pair (L1 WGs)
  __shared__ float4 pL[2304];     // 36.9KB partials [c(32)][bq(8)][slot8 pad9]

  {  // one-time weight gather (cached loads; immutable)
    if (!isL1A) {
      const float* A0 = gA ? a.Wrh0 : a.Wzh0;
      for (int idx = tid; idx < 4096; idx += BDIM) {
        int c4 = idx >> 9, k = idx & 511;
        wA4[idx] = *(const float4*)(A0 + (size_t)k * 512 + jA0 + c4 * 4);
      }
    } else {
      const float* A0 = gA ? a.Wrx1 : a.Wzx1;   // k in [0,512): x-input (y1)
      const float* A1 = gA ? a.Wrh1 : a.Wzh1;   // k in [512,1024): h_prev (y2)
      for (int idx = tid; idx < 4096; idx += BDIM) {
        int c4 = idx >> 10, k = idx & 1023;
        const float* M = (k < 512) ? A0 : A1;
        wA4[idx] = *(const float4*)(M + (size_t)(k & 511) * 512 + jA0 + c4 * 4);
      }
    }
    if (isG0) {
      for (int idx = tid; idx < 2048; idx += BDIM) {
        int c4 = idx >> 9, k = idx & 511;
        wB4[idx] = *(const float4*)(a.Wgh0 + (size_t)k * 512 + jB0 + c4 * 4);
      }
    } else {
      for (int idx = tid; idx < 2048; idx += BDIM) {
        int c4 = idx >> 10, k = idx & 1023;
        const float* M = (k < 512) ? a.Wgx1 : a.Wgh1;
        wB4[idx] = *(const float4*)(M + (size_t)(k & 511) * 512 + jB0 + c4 * 4);
      }
    }
    {  // x-slice weights: 16 cols of the concatenated {Wzx0,Wrx0,Wgx0} space
      const float* M = (jX0 < 512) ? a.Wzx0 : (jX0 < 1024 ? a.Wrx0 : a.Wgx0);
      int base = jX0 & 511;
      for (int idx = tid; idx < 512; idx += BDIM) {
        int c4 = idx >> 7, k = idx & 127;
        xw4[idx] = *(const float4*)(M + (size_t)k * 512 + base + c4 * 4);
      }
    }
    if (isL1A)
      for (int idx = tid; idx < 512; idx += BDIM)
        wO2[idx] = *(const float2*)(a.Wout + (size_t)idx * 128 + jO);
  }
  const float* bAv = isL1A ? (gA ? a.br1 : a.bz1) : (gA ? a.br0 : a.bz0);
  float biasA = 0.f, biasB = 0.f, boutc = 0.f;
  if (tid < CA * 8) biasA = bAv[jA0 + (tid >> 3)];
  if (tid < CB * 8) biasB = (isG0 ? a.bg0 : a.bg1)[jB0 + (tid >> 3)];
  if (isL1A && tid >= 128 && tid < 144) boutc = a.bout[jO + ((tid >> 3) & 1)];
  __syncthreads();

  const float* XT = ws + XT_OFF;

  for (int tau = 0; tau <= S_ + 1; ++tau) {
    const bool doL0 = (tau < S_);
    const bool doL1 = (tau >= 1) && (tau <= S_);
    const bool outW = isL1A && (tau >= 2);
    const float* y1p = ws + Y1_OFF + (size_t)((tau + 1) & 1) * HB;   // y1[tau-1]
    const float* y2p = ws + Y2_OFF + (size_t)(tau & 1) * HB;         // y2[tau-2]
    float* y1w = ws + Y1_OFF + (size_t)(tau & 1) * HB;               // y1[tau]
    float* y2w = ws + Y2_OFF + (size_t)((tau + 1) & 1) * HB;         // y2[tau-1]
    const float* XNr = ws + XN_OFF + (size_t)(tau & 1) * XN_SLOT;        // XN[tau]
    float*       XNw = ws + XN_OFF + (size_t)((tau + 1) & 1) * XN_SLOT;  // XN[tau+1]

    // ================= phase A: z & r (+ fused outproj on L1) =================
    const bool actR = isL1A ? doL1 : doL0;
    const int  cR = tid >> 3, bqR = tid & 7;
    const size_t jbA = (size_t)(jA0 + cR) * 64 + b0 + bqR * 4;
    // hp prefetch for r roles (post-barrier: y1p/y2p are valid now; use after reduce)
    float4 hpA = make_float4(0.f, 0.f, 0.f, 0.f);
    if (gA && actR && tid < CA * 8)
      hpA = llc_load4((isL1A ? y2p : y1p) + jbA);

    float4 acc[32];
    #pragma unroll
    for (int c = 0; c < 32; ++c) acc[c] = make_float4(0.f, 0.f, 0.f, 0.f);
    float4 accO0 = make_float4(0.f, 0.f, 0.f, 0.f);
    float4 accO1 = make_float4(0.f, 0.f, 0.f, 0.f);

    if (!isL1A) {
      if (doL0) {
        #pragma unroll
        for (int i = 0; i < 8; ++i) {        // y1[tau-1] @ Wzh0/Wrh0, K=512
          const int k = i * 64 + kt;
          float4 h = llc_load4(y1p + (size_t)k * 64 + b0 + b4);
          fma32L(acc, wA4, k, h);
        }
      }
    } else {
      if (doL1) {
        #pragma unroll
        for (int i = 0; i < 8; ++i) {        // y1[tau-1] @ Wzx1/Wrx1
          const int k = i * 64 + kt;
          float4 h = llc_load4(y1p + (size_t)k * 64 + b0 + b4);
          fma16La(acc, wA4, k, h);
        }
      }
      if (doL1 || outW) {
        #pragma unroll
        for (int i = 0; i < 8; ++i) {        // y2[tau-2] @ Wzh1/Wrh1 + outproj fold
          const int k = i * 64 + kt;
          float4 h = llc_load4(y2p + (size_t)k * 64 + b0 + b4);
          fma16La(acc, wA4, 512 + k, h);
          float2 wo = wO2[k];
          fmas(accO0, wo.x, h); fmas(accO1, wo.y, h);
        }
      }
    }
    if (actR) {
      if (!isL1A) {
        #pragma unroll
        for (int c = 0; c < 32; ++c) red3(acc[c]);
        if ((lane & 56) == 0) {
          #pragma unroll
          for (int c = 0; c < 32; ++c) pL[(c * 8 + bq) * 9 + wv] = acc[c];
        }
      } else {
        #pragma unroll
        for (int c = 0; c < 16; ++c) red3(acc[c]);
        if ((lane & 56) == 0) {
          #pragma unroll
          for (int c = 0; c < 16; ++c) pL[(c * 8 + bq) * 9 + wv] = acc[c];
        }
      }
    }
    if (outW) {
      red3(accO0); red3(accO1);
      if ((lane & 56) == 0) {
        pL[(16 * 8 + bq) * 9 + wv] = accO0;
        pL[(17 * 8 + bq) * 9 + wv] = accO1;
      }
    }
    __syncthreads();
    if (actR && tid < CA * 8) {
      const float4* row = &pL[(cR * 8 + bqR) * 9];
      float4 s = make_float4(biasA, biasA, biasA, biasA);
      #pragma unroll
      for (int w = 0; w < 8; ++w) {
        float4 p = row[w];
        s.x += p.x; s.y += p.y; s.z += p.z; s.w += p.w;
      }
      if (!isL1A) {   // add precomputed x-projection
        float4 xn = llc_load4(XNr + (size_t)((gA ? 512 : 0) + jA0 + cR) * 64 + b0 + bqR * 4);
        s.x += xn.x; s.y += xn.y; s.z += xn.z; s.w += xn.w;
      }
      float4 v;
      v.x = 1.0f / (1.0f + __expf(-s.x)); v.y = 1.0f / (1.0f + __expf(-s.y));
      v.z = 1.0f / (1.0f + __expf(-s.z)); v.w = 1.0f / (1.0f + __expf(-s.w));
      if (gA == 0) {
        llc_store4(ws + (isL1A ? Z1_OFF : Z0_OFF) + jbA, v);
      } else {
        v.x *= hpA.x; v.y *= hpA.y; v.z *= hpA.z; v.w *= hpA.w;
        llc_store4(ws + (isL1A ? RH1_OFF : RH0_OFF) + jbA, v);
      }
    } else if (isL1A && outW && tid >= 128 && tid < 144) {
      const int oc = (tid >> 3) & 1, bqc = tid & 7;
      const float4* row = &pL[((16 + oc) * 8 + bqc) * 9];
      float4 s = make_float4(boutc, boutc, boutc, boutc);
      #pragma unroll
      for (int w = 0; w < 8; ++w) {
        float4 p = row[w];
        s.x += p.x; s.y += p.y; s.z += p.z; s.w += p.w;
      }
      const size_t ob = ((size_t)(b0 + bqc * 4) * 1024 + (tau - 2)) * 128 + jO + oc;
      a.out[ob]          = s.x;
      a.out[ob + 131072] = s.y;
      a.out[ob + 262144] = s.z;
      a.out[ob + 393216] = s.w;
    }

    grid_barrier(bhalf, grp, 2u * tau + 1u);   // rh/z visible half-wide

    // ================= phase B: g + h update; x-slice for XN[tau+1] =================
    const bool actB = isG0 ? doL0 : doL1;
    const size_t jbB = (size_t)(jB0 + (tid >> 3)) * 64 + b0 + (tid & 7) * 4;
    float4 zB  = make_float4(0.f, 0.f, 0.f, 0.f);
    float4 hpB = make_float4(0.f, 0.f, 0.f, 0.f);
    if (actB && tid < CB * 8) {     // prefetch (post-barrier; hides under dots)
      zB  = llc_load4(ws + (isG0 ? Z0_OFF : Z1_OFF) + jbB);
      hpB = llc_load4((isG0 ? y1p : y2p) + jbB);
    }
    float4 accB[16];
    #pragma unroll
    for (int c = 0; c < 16; ++c) accB[c] = make_float4(0.f, 0.f, 0.f, 0.f);
    if (actB) {
      if (isG0) {
        #pragma unroll
        for (int i = 0; i < 8; ++i) {        // rh0 @ Wgh0, K=512
          const int k = i * 64 + kt;
          float4 h = llc_load4(ws + RH0_OFF + (size_t)k * 64 + b0 + b4);
          fma16Lb(accB, wB4, k, h);
        }
      } else {
        #pragma unroll
        for (int i = 0; i < 8; ++i) {        // y1[tau-1] @ Wgx1
          const int k = i * 64 + kt;
          float4 h = llc_load4(y1p + (size_t)k * 64 + b0 + b4);
          fma8La(accB, wB4, k, h);
        }
        #pragma unroll
        for (int i = 0; i < 8; ++i) {        // rh1 @ Wgh1
          const int k = i * 64 + kt;
          float4 h = llc_load4(ws + RH1_OFF + (size_t)k * 64 + b0 + b4);
          fma8La(accB, wB4, 512 + k, h);
        }
      }
      #pragma unroll
      for (int c = 0; c < 8; ++c) red3(accB[c]);
      if (isG0) {
        #pragma unroll
        for (int c = 8; c < 16; ++c) red3(accB[c]);
      }
      if ((lane & 56) == 0) {
        for (int c = 0; c < CB; ++c) pL[(c * 8 + bq) * 9 + wv] = accB[c];
      }
    }
    // x-slice: XN[tau+1] = x[tau+1] @ {Wzx0,Wrx0,Wgx0} cols [jX0,jX0+16)
    const bool doX = (tau < S_ - 1);
    float4 accX[16];
    if (doX) {
      #pragma unroll
      for (int c = 0; c < 16; ++c) accX[c] = make_float4(0.f, 0.f, 0.f, 0.f);
      if (a.use_xt) {
        const float* XTt = XT + (size_t)(tau + 1) * 8192;
        #pragma unroll
        for (int i = 0; i < 2; ++i) {
          const int k = i * 64 + kt;
          float4 xv = *(const float4*)(XTt + (size_t)k * 64 + b0 + b4);
          fma16X(accX, xw4, k, xv);
        }
      } else {
        #pragma unroll
        for (int i = 0; i < 2; ++i) {
          const int k = i * 64 + kt;
          float4 xv;
          xv.x = a.xin[(size_t)(b0 + b4 + 0) * 131072 + (size_t)(tau + 1) * 128 + k];
          xv.y = a.xin[(size_t)(b0 + b4 + 1) * 131072 + (size_t)(tau + 1) * 128 + k];
          xv.z = a.xin[(size_t)(b0 + b4 + 2) * 131072 + (size_t)(tau + 1) * 128 + k];
          xv.w = a.xin[(size_t)(b0 + b4 + 3) * 131072 + (size_t)(tau + 1) * 128 + k];
          fma16X(accX, xw4, k, xv);
        }
      }
      #pragma unroll
      for (int c = 0; c < 16; ++c) red3(accX[c]);
      if ((lane & 56) == 0) {
        #pragma unroll
        for (int c = 0; c < 16; ++c) pL[((16 + c) * 8 + bq) * 9 + wv] = accX[c];
      }
    }
    __syncthreads();
    if (actB && tid < CB * 8) {
      const int c = tid >> 3, bqc = tid & 7;
      const float4* row = &pL[(c * 8 + bqc) * 9];
      float4 s = make_float4(biasB, biasB, biasB, biasB);
      #pragma unroll
      for (int w = 0; w < 8; ++w) {
        float4 p = row[w];
        s.x += p.x; s.y += p.y; s.z += p.z; s.w += p.w;
      }
      if (isG0) {     // add precomputed xg0
        float4 xn = llc_load4(XNr + (size_t)(1024 + jB0 + c) * 64 + b0 + bqc * 4);
        s.x += xn.x; s.y += xn.y; s.z += xn.z; s.w += xn.w;
      }
      float4 g;
      g.x = tanhf(s.x); g.y = tanhf(s.y); g.z = tanhf(s.z); g.w = tanhf(s.w);
      float4 hn;
      hn.x = fmaf(zB.x, hpB.x - g.x, g.x);
      hn.y = fmaf(zB.y, hpB.y - g.y, g.y);
      hn.z = fmaf(zB.z, hpB.z - g.z, g.z);
      hn.w = fmaf(zB.w, hpB.w - g.w, g.w);
      llc_store4((isG0 ? y1w : y2w) + jbB, hn);
    }
    if (doX && tid < 128) {
      const int c = tid >> 3, bqc = tid & 7;
      const float4* row = &pL[((16 + c) * 8 + bqc) * 9];
      float4 s = make_float4(0.f, 0.f, 0.f, 0.f);
      #pragma unroll
      for (int w = 0; w < 8; ++w) {
        float4 p = row[w];
        s.x += p.x; s.y += p.y; s.z += p.z; s.w += p.w;
      }
      llc_store4(XNw + (size_t)(jX0 + c) * 64 + b0 + bqc * 4, s);
    }

    grid_barrier(bhalf, grp, 2u * tau + 2u);   // h slabs visible for next step
  }
}

// ---------------- final hidden states: out[BSO + b*1024 + l*512 + j] ----------------
__global__ void k_hidden(const float* __restrict__ ws, float* __restrict__ out) {
  int idx = blockIdx.x * 256 + threadIdx.x;   // 65536
  int b = idx >> 10, rem = idx & 1023, l = rem >> 9, j = rem & 511;
  // y1[1023] at slot 1; y2[1023] written at tau=1024 -> slot (1024+1)&1 = 1
  const float* src = ws + (l ? Y2_OFF : Y1_OFF) + HB + (size_t)j * 64 + b;
  out[(size_t)B_ * S_ * O_ + idx] = *src;
}

// ---------------- launch ----------------
extern "C" void kernel_launch(void* const* d_in, const int* in_sizes, int n_in,
                              void* d_out, int out_size, void* d_ws, size_t ws_size,
                              hipStream_t stream) {
  const float* input  = (const float*)d_in[0];
  const float* hidden = (const float*)d_in[1];
  const float* Wzx0 = (const float*)d_in[2],  *Wzh0 = (const float*)d_in[3],  *bz0 = (const float*)d_in[4];
  const float* Wrx0 = (const float*)d_in[5],  *Wrh0 = (const float*)d_in[6],  *br0 = (const float*)d_in[7];
  const float* Wgx0 = (const float*)d_in[8],  *Wgh0 = (const float*)d_in[9],  *bg0 = (const float*)d_in[10];
  const float* Wzx1 = (const float*)d_in[11], *Wzh1 = (const float*)d_in[12], *bz1 = (const float*)d_in[13];
  const float* Wrx1 = (const float*)d_in[14], *Wrh1 = (const float*)d_in[15], *br1 = (const float*)d_in[16];
  const float* Wgx1 = (const float*)d_in[17], *Wgh1 = (const float*)d_in[18], *bg1 = (const float*)d_in[19];
  const float* Wout = (const float*)d_in[20], *bout = (const float*)d_in[21];
  float* ws = (float*)d_ws;
  float* out = (float*)d_out;

  const int use_xt = (ws_size >= WS_NEED_XT_BYTES) ? 1 : 0;

  k_init<<<265, 256, 0, stream>>>(hidden, ws);
  if (use_xt) k_transpose_x<<<2048, 256, 0, stream>>>(input, ws + XT_OFF);
  k_xn0<<<1536, 64, 0, stream>>>(input, Wzx0, Wrx0, Wgx0, ws, use_xt);

  ScanArgs sa{ws, input, out,
              Wzx0, Wzh0, bz0, Wrx0, Wrh0, br0, Wgx0, Wgh0, bg0,
              Wzx1, Wzh1, bz1, Wrx1, Wrh1, br1, Wgx1, Wgh1, bg1,
              Wout, bout, use_xt};
  k_scan<<<dim3(NWG), dim3(BDIM), 0, stream>>>(sa);

  k_hidden<<<256, 256, 0, stream>>>(ws, out);
}